// Round 3
// baseline (86.795 us; speedup 1.0000x reference)
//
#include <hip/hip_runtime.h>
#include <hip/hip_bf16.h>

// SparseLinear: out[b,l] = dot(embed[b,:], weight[shortlist[b,l],:]) + bias[shortlist[b,l]]
// B=256, L=1000, D=512, V=670092. Memory-bound gather of 2KB rows.
// R3: 4 rows in flight per wave (8x float4 outstanding), one butterfly per 4 rows.

#define BB 256
#define LL 1000
#define DD 512
#define LPB 40    // l's per block: 4 waves x 10 rows
#define ITERS 10  // rows per wave

#define DOT8(s, p, q) (e0.x*(p).x + e0.y*(p).y + e0.z*(p).z + e0.w*(p).w \
                     + e1.x*(q).x + e1.y*(q).y + e1.z*(q).z + e1.w*(q).w)

__global__ __launch_bounds__(256) void sparse_linear_kernel(
    const float* __restrict__ embed,      // [B, D]
    const int*   __restrict__ shortlist,  // [B, L]
    const float* __restrict__ weight,     // [V, D]
    const float* __restrict__ bias,       // [V, 1]
    float*       __restrict__ out)        // [B, L]
{
    const int b    = blockIdx.y;
    const int lane = threadIdx.x & 63;
    const int wave = threadIdx.x >> 6;   // 0..3

    // Each lane holds 8 embed floats: embed[b, lane*8 .. lane*8+7].
    const float4* e4 = reinterpret_cast<const float4*>(embed + (size_t)b * DD + lane * 8);
    const float4 e0 = e4[0];
    const float4 e1 = e4[1];

    // Wave handles l = lbase + 4*i, i in [0,10).
    const int lbase = blockIdx.x * LPB + wave;

    // Prefetch all 10 indices for this wave (lanes 0..9), broadcast later.
    int pidx = 0;
    if (lane < ITERS)
        pidx = shortlist[(size_t)b * LL + lbase + 4 * lane];

    float* orow = out + (size_t)b * LL + lbase;

    // Two groups of 4 rows, then a tail of 2.
    #pragma unroll
    for (int g = 0; g < 8; g += 4) {
        const int idx0 = __shfl(pidx, g);
        const int idx1 = __shfl(pidx, g + 1);
        const int idx2 = __shfl(pidx, g + 2);
        const int idx3 = __shfl(pidx, g + 3);

        // Early bias loads (latency hides under row fetches).
        float bval = 0.0f;
        if      (lane == 0) bval = bias[idx0];
        else if (lane == 1) bval = bias[idx1];
        else if (lane == 2) bval = bias[idx2];
        else if (lane == 3) bval = bias[idx3];

        const float4* w0p = reinterpret_cast<const float4*>(weight + (size_t)idx0 * DD + lane * 8);
        const float4* w1p = reinterpret_cast<const float4*>(weight + (size_t)idx1 * DD + lane * 8);
        const float4* w2p = reinterpret_cast<const float4*>(weight + (size_t)idx2 * DD + lane * 8);
        const float4* w3p = reinterpret_cast<const float4*>(weight + (size_t)idx3 * DD + lane * 8);
        const float4 a0 = w0p[0], a1 = w0p[1];
        const float4 f0 = w1p[0], f1 = w1p[1];
        const float4 c0 = w2p[0], c1 = w2p[1];
        const float4 d0 = w3p[0], d1 = w3p[1];

        float s0 = DOT8(s0, a0, a1);
        float s1 = DOT8(s1, f0, f1);
        float s2 = DOT8(s2, c0, c1);
        float s3 = DOT8(s3, d0, d1);

        // One 64-lane butterfly for all 4 rows.
        #pragma unroll
        for (int off = 32; off > 0; off >>= 1) {
            s0 += __shfl_down(s0, off);
            s1 += __shfl_down(s1, off);
            s2 += __shfl_down(s2, off);
            s3 += __shfl_down(s3, off);
        }

        const float b1v = __shfl(bval, 1);
        const float b2v = __shfl(bval, 2);
        const float b3v = __shfl(bval, 3);
        if (lane == 0) {
            orow[4 * g]       = s0 + bval;
            orow[4 * (g + 1)] = s1 + b1v;
            orow[4 * (g + 2)] = s2 + b2v;
            orow[4 * (g + 3)] = s3 + b3v;
        }
    }

    // Tail: rows 8, 9.
    {
        const int idx0 = __shfl(pidx, 8);
        const int idx1 = __shfl(pidx, 9);

        float bval = 0.0f;
        if      (lane == 0) bval = bias[idx0];
        else if (lane == 1) bval = bias[idx1];

        const float4* w0p = reinterpret_cast<const float4*>(weight + (size_t)idx0 * DD + lane * 8);
        const float4* w1p = reinterpret_cast<const float4*>(weight + (size_t)idx1 * DD + lane * 8);
        const float4 a0 = w0p[0], a1 = w0p[1];
        const float4 f0 = w1p[0], f1 = w1p[1];

        float s0 = DOT8(s0, a0, a1);
        float s1 = DOT8(s1, f0, f1);

        #pragma unroll
        for (int off = 32; off > 0; off >>= 1) {
            s0 += __shfl_down(s0, off);
            s1 += __shfl_down(s1, off);
        }

        const float b1v = __shfl(bval, 1);
        if (lane == 0) {
            orow[4 * 8] = s0 + bval;
            orow[4 * 9] = s1 + b1v;
        }
    }
}

extern "C" void kernel_launch(void* const* d_in, const int* in_sizes, int n_in,
                              void* d_out, int out_size, void* d_ws, size_t ws_size,
                              hipStream_t stream) {
    const float* embed     = (const float*)d_in[0];  // [256, 512] f32
    const int*   shortlist = (const int*)  d_in[1];  // [256, 1000] int
    const float* weight    = (const float*)d_in[2];  // [670092, 512] f32
    const float* bias      = (const float*)d_in[3];  // [670092, 1] f32
    float*       out       = (float*)d_out;          // [256, 1000] f32

    dim3 grid((LL + LPB - 1) / LPB, BB);
    sparse_linear_kernel<<<grid, 256, 0, stream>>>(embed, shortlist, weight, bias, out);
}